// Round 5
// baseline (310.135 us; speedup 1.0000x reference)
//
#include <hip/hip_runtime.h>
#include <hip/hip_bf16.h>

#define N_NODES 4096
#define E_EDGES 131072
#define DIN_    512
#define DM_     256
#define DFF_    2048
#define EPS_    1e-5f
#define NSPLIT  8

typedef __attribute__((ext_vector_type(8))) short bf16x8;   // 8 bf16 = 4 VGPR
typedef __attribute__((ext_vector_type(4))) float f32x4;

__device__ __forceinline__ short f2b(float f) {
    union { float f; unsigned u; } x; x.f = f;
    unsigned r = x.u + 0x7fff + ((x.u >> 16) & 1);   // RNE
    return (short)(r >> 16);
}

// ---------------------------------------------------------------------------
// casts
// ---------------------------------------------------------------------------
__global__ __launch_bounds__(256)
void castf2b_kernel(const float* __restrict__ s, short* __restrict__ d, int n4) {
    int i = blockIdx.x * 256 + threadIdx.x;
    if (i >= n4) return;
    float4 v = reinterpret_cast<const float4*>(s)[i];
    union { short s[4]; int2 v; } o;
    o.s[0] = f2b(v.x); o.s[1] = f2b(v.y); o.s[2] = f2b(v.z); o.s[3] = f2b(v.w);
    reinterpret_cast<int2*>(d)[i] = o.v;
}

// W_gcn [512][256] f32 -> WgT [256][512] bf16
__global__ __launch_bounds__(256)
void wgt_kernel(const float* __restrict__ W, short* __restrict__ WT) {
    __shared__ float t[32][33];
    const int tx = threadIdx.x & 31, ty = threadIdx.x >> 5;
    const int bk = blockIdx.x * 32, bn = blockIdx.y * 32;
    #pragma unroll
    for (int i = 0; i < 4; ++i) {
        int r = ty + i * 8;
        t[r][tx] = W[(size_t)(bk + r) * DM_ + bn + tx];
    }
    __syncthreads();
    #pragma unroll
    for (int i = 0; i < 4; ++i) {
        int r = ty + i * 8;
        WT[(size_t)(bn + r) * DIN_ + bk + tx] = f2b(t[tx][r]);
    }
}

// qkv bf16 [4096][768] cols 512..767 -> VT [256][4096] (row d = head*128+dh)
__global__ __launch_bounds__(256)
void vt_kernel(const short* __restrict__ qkv, short* __restrict__ VT) {
    __shared__ short t[32][33];
    const int tx = threadIdx.x & 31, ty = threadIdx.x >> 5;
    const int bn = blockIdx.x * 32, bd = blockIdx.y * 32;
    #pragma unroll
    for (int i = 0; i < 4; ++i) {
        int r = ty + i * 8;
        t[r][tx] = qkv[(size_t)(bn + r) * 768 + 512 + bd + tx];
    }
    __syncthreads();
    #pragma unroll
    for (int i = 0; i < 4; ++i) {
        int r = ty + i * 8;
        VT[(size_t)(bd + r) * N_NODES + bn + tx] = t[tx][r];
    }
}

// ---------------------------------------------------------------------------
// bf16 MFMA GEMM: C = A[M,K] @ B^T  (B given row-major [N,K]) + bias, epi.
// 128x128 tile, 4 waves (each 64x64), BK=32, A staged in LDS (XOR-swizzled
// 16B chunks), B frags read direct from global (L2-resident weights).
// ---------------------------------------------------------------------------
template<bool BF16OUT, bool RELU, bool SPLITK>
__global__ __launch_bounds__(256)
void mgemm_kernel(const short* __restrict__ A, const short* __restrict__ B,
                  const float* __restrict__ bias,
                  float* __restrict__ Cf, short* __restrict__ Cb,
                  int M, int N, int K, int lda, int ldb, int ldc, int kchunk)
{
    __shared__ short As[128 * 32];    // 8 KB
    const int tid = threadIdx.x;
    const int lane = tid & 63, w = tid >> 6;
    const int c = lane & 15, g = lane >> 4;
    const int wm = (w >> 1) * 64, wn = (w & 1) * 64;
    const int bm = blockIdx.y * 128, bn = blockIdx.x * 128;
    int k0 = 0, kend = K;
    if (SPLITK) { k0 = blockIdx.z * kchunk; kend = min(K, k0 + kchunk); }

    const int srow = tid >> 1;               // 0..127
    const int kc0  = (tid & 1) * 2;          // 16B-chunk 0 or 2
    const short* Ag = A + (size_t)(bm + srow) * lda;

    f32x4 acc[4][4] = {};
    for (int kb = k0; kb < kend; kb += 32) {
        #pragma unroll
        for (int i = 0; i < 2; ++i) {
            int kc = kc0 + i;
            bf16x8 v = *reinterpret_cast<const bf16x8*>(Ag + kb + kc * 8);
            int kcs = kc ^ ((srow >> 1) & 3);
            *reinterpret_cast<bf16x8*>(&As[srow * 32 + kcs * 8]) = v;
        }
        __syncthreads();
        bf16x8 bf[4];
        #pragma unroll
        for (int nf = 0; nf < 4; ++nf)
            bf[nf] = *reinterpret_cast<const bf16x8*>(
                B + (size_t)(bn + wn + nf * 16 + c) * ldb + kb + g * 8);
        bf16x8 af[4];
        #pragma unroll
        for (int mf = 0; mf < 4; ++mf) {
            int row = wm + mf * 16 + c;
            int kcs = g ^ ((row >> 1) & 3);
            af[mf] = *reinterpret_cast<const bf16x8*>(&As[row * 32 + kcs * 8]);
        }
        #pragma unroll
        for (int mf = 0; mf < 4; ++mf)
            #pragma unroll
            for (int nf = 0; nf < 4; ++nf)
                acc[mf][nf] = __builtin_amdgcn_mfma_f32_16x16x32_bf16(
                    af[mf], bf[nf], acc[mf][nf], 0, 0, 0);
        __syncthreads();
    }
    #pragma unroll
    for (int mf = 0; mf < 4; ++mf) {
        const int row = bm + wm + mf * 16 + g * 4;
        #pragma unroll
        for (int nf = 0; nf < 4; ++nf) {
            const int col = bn + wn + nf * 16 + c;
            float bv = bias ? bias[col] : 0.f;
            #pragma unroll
            for (int v = 0; v < 4; ++v) {
                float val = acc[mf][nf][v];
                size_t o = (size_t)(row + v) * ldc + col;
                if (SPLITK) {
                    if (blockIdx.z == 0) val += bv;
                    atomicAdd(&Cf[o], val);
                } else {
                    val += bv;
                    if (RELU) val = fmaxf(val, 0.f);
                    if (BF16OUT) Cb[o] = f2b(val);
                    else         Cf[o] = val;
                }
            }
        }
    }
}

// ---------------------------------------------------------------------------
// Flash attention, KV-split, XCD-locality decode. 1D grid of 1024 blocks,
// 256 threads (4 waves x 16 q-rows = 64 q-rows/block).
//   xcd  = bid & 7   (round-robin block->XCD heuristic)
//   pair = 2*xcd + ((bid>>3) & 1)  -> hd = pair>>3, sp = pair&7
//   qt   = bid >> 4  (0..63)
// Each XCD serves 2 (hd,sp) pairs -> K/V working set 524 KB, L2-resident.
// ---------------------------------------------------------------------------
__global__ __launch_bounds__(256)
void fattn_kernel(const short* __restrict__ qkv, const short* __restrict__ VT,
                  short* __restrict__ Opart, float* __restrict__ ml)
{
    const int bid = blockIdx.x;
    const int j = bid >> 3;
    const int pair = 2 * (bid & 7) + (j & 1);
    const int hd = pair >> 3, sp = pair & 7;
    const int qt = j >> 1;
    const int w = threadIdx.x >> 6, lane = threadIdx.x & 63;
    const int c = lane & 15, g = lane >> 4;
    const int q0 = qt * 64 + w * 16;
    __shared__ short Plds[4][16][88];    // padded: 176B row stride -> 2-way

    const short* Q  = qkv + (size_t)q0 * 768 + hd * 128;
    const short* Kb = qkv + 256 + hd * 128;
    const short* Vt = VT + (size_t)hd * 128 * N_NODES;

    bf16x8 qf[4];
    #pragma unroll
    for (int ks = 0; ks < 4; ++ks)
        qf[ks] = *reinterpret_cast<const bf16x8*>(Q + (size_t)c * 768 + ks * 32 + g * 8);

    f32x4 O[8] = {};
    float m[4]  = {-1e30f, -1e30f, -1e30f, -1e30f};
    float lsum[4] = {};
    const float sc = 0.08838834764831845f;   // 1/sqrt(128)

    for (int kt = sp * 8; kt < sp * 8 + 8; ++kt) {
        const int key0 = kt * 64;
        f32x4 S[4] = {};
        #pragma unroll
        for (int nf = 0; nf < 4; ++nf) {
            const short* Kr = Kb + (size_t)(key0 + nf * 16 + c) * 768;
            #pragma unroll
            for (int ks = 0; ks < 4; ++ks) {
                bf16x8 kf = *reinterpret_cast<const bf16x8*>(Kr + ks * 32 + g * 8);
                S[nf] = __builtin_amdgcn_mfma_f32_16x16x32_bf16(qf[ks], kf, S[nf], 0, 0, 0);
            }
        }
        // online softmax; row r = 4g+v, col = nf*16+c
        float sv[4][4];
        float mx[4];
        #pragma unroll
        for (int v = 0; v < 4; ++v) {
            #pragma unroll
            for (int nf = 0; nf < 4; ++nf) sv[nf][v] = S[nf][v] * sc;
            mx[v] = fmaxf(fmaxf(sv[0][v], sv[1][v]), fmaxf(sv[2][v], sv[3][v]));
        }
        #pragma unroll
        for (int off = 1; off <= 8; off <<= 1)
            #pragma unroll
            for (int v = 0; v < 4; ++v) mx[v] = fmaxf(mx[v], __shfl_xor(mx[v], off));
        float scl[4];
        #pragma unroll
        for (int v = 0; v < 4; ++v) {
            float mn = fmaxf(m[v], mx[v]);
            scl[v] = __expf(m[v] - mn);
            m[v] = mn;
        }
        float rs[4] = {};
        #pragma unroll
        for (int nf = 0; nf < 4; ++nf)
            #pragma unroll
            for (int v = 0; v < 4; ++v) {
                float p = __expf(sv[nf][v] - m[v]);
                rs[v] += p;
                Plds[w][4 * g + v][nf * 16 + c] = f2b(p);
            }
        #pragma unroll
        for (int off = 1; off <= 8; off <<= 1)
            #pragma unroll
            for (int v = 0; v < 4; ++v) rs[v] += __shfl_xor(rs[v], off);
        #pragma unroll
        for (int v = 0; v < 4; ++v) lsum[v] = lsum[v] * scl[v] + rs[v];
        #pragma unroll
        for (int nf2 = 0; nf2 < 8; ++nf2)
            #pragma unroll
            for (int v = 0; v < 4; ++v) O[nf2][v] *= scl[v];
        bf16x8 pa[2];
        #pragma unroll
        for (int ks = 0; ks < 2; ++ks)
            pa[ks] = *reinterpret_cast<const bf16x8*>(&Plds[w][c][ks * 32 + g * 8]);
        #pragma unroll
        for (int nf2 = 0; nf2 < 8; ++nf2) {
            const short* Vr = Vt + (size_t)(nf2 * 16 + c) * N_NODES + key0;
            #pragma unroll
            for (int ks = 0; ks < 2; ++ks) {
                bf16x8 vf = *reinterpret_cast<const bf16x8*>(Vr + ks * 32 + g * 8);
                O[nf2] = __builtin_amdgcn_mfma_f32_16x16x32_bf16(pa[ks], vf, O[nf2], 0, 0, 0);
            }
        }
    }
    // write partials: Opart[((hd*NSPLIT+sp)*4096 + row)*128 + dh], ml[...*2]
    const size_t pbase = ((size_t)hd * NSPLIT + sp) * N_NODES;
    #pragma unroll
    for (int v = 0; v < 4; ++v) {
        const int row = q0 + 4 * g + v;
        const size_t rowo = (pbase + row) * 128;
        #pragma unroll
        for (int nf2 = 0; nf2 < 8; ++nf2)
            Opart[rowo + nf2 * 16 + c] = f2b(O[nf2][v]);
        if (c == 0) {
            ml[(pbase + row) * 2 + 0] = m[v];
            ml[(pbase + row) * 2 + 1] = lsum[v];
        }
    }
}

// combine NSPLIT partials -> attnb bf16 [4096][256]; grid (4096, 2), 128 thr
__global__ __launch_bounds__(128)
void attn_combine_kernel(const short* __restrict__ Opart, const float* __restrict__ ml,
                         short* __restrict__ attnb)
{
    const int row = blockIdx.x, hd = blockIdx.y, d = threadIdx.x;
    float ms[NSPLIT], ls[NSPLIT];
    float mmax = -1e30f;
    #pragma unroll
    for (int s = 0; s < NSPLIT; ++s) {
        const size_t p = ((size_t)hd * NSPLIT + s) * N_NODES + row;
        ms[s] = ml[p * 2 + 0];
        ls[s] = ml[p * 2 + 1];
        mmax = fmaxf(mmax, ms[s]);
    }
    float lt = 0.f, acc = 0.f;
    #pragma unroll
    for (int s = 0; s < NSPLIT; ++s) {
        const float wgt = __expf(ms[s] - mmax);
        lt += wgt * ls[s];
        const size_t p = ((size_t)hd * NSPLIT + s) * N_NODES + row;
        union { short s; unsigned short u; } b; b.s = Opart[p * 128 + d];
        union { unsigned u; float f; } cv; cv.u = ((unsigned)b.u) << 16;
        acc += wgt * cv.f;
    }
    attnb[(size_t)row * DM_ + hd * 128 + d] = f2b(acc / lt);
}

// ---------------------------------------------------------------------------
// GCN: degree, CSR build, gather-aggregate
// ---------------------------------------------------------------------------
__global__ void deg_init_kernel(float* deg, int* count) {
    int i = blockIdx.x * 256 + threadIdx.x;
    if (i < N_NODES) { deg[i] = 1.0f; count[i] = 0; }
}
__global__ void deg_accum_kernel(const int* __restrict__ dst,
                                 const float* __restrict__ w,
                                 float* deg, int* count) {
    int e = blockIdx.x * 256 + threadIdx.x;
    if (e < E_EDGES) {
        int d = dst[e];
        atomicAdd(&deg[d], w[e]);
        atomicAdd(&count[d], 1);
    }
}
__global__ void dinv_kernel(float* deg) {
    int i = blockIdx.x * 256 + threadIdx.x;
    if (i < N_NODES) deg[i] = rsqrtf(deg[i]);
}
__global__ __launch_bounds__(256)
void csr_scan_kernel(const int* __restrict__ count, int* __restrict__ start,
                     int* __restrict__ cursor) {
    __shared__ int sum[256];
    const int tid = threadIdx.x;
    const int base = tid * 16;
    int loc[16]; int s = 0;
    #pragma unroll
    for (int i = 0; i < 16; ++i) { loc[i] = count[base + i]; s += loc[i]; }
    sum[tid] = s;
    __syncthreads();
    for (int off = 1; off < 256; off <<= 1) {
        int v = (tid >= off) ? sum[tid - off] : 0;
        __syncthreads();
        sum[tid] += v;
        __syncthreads();
    }
    int run = sum[tid] - s;
    #pragma unroll
    for (int i = 0; i < 16; ++i) {
        start[base + i] = run;
        cursor[base + i] = run;
        run += loc[i];
    }
    if (tid == 255) start[N_NODES] = run;
}
__global__ void csr_fill_kernel(const int* __restrict__ src, const int* __restrict__ dst,
                                const float* __restrict__ w, const float* __restrict__ dinv,
                                int* __restrict__ cursor,
                                int* __restrict__ csr_src, float* __restrict__ csr_nrm) {
    int e = blockIdx.x * 256 + threadIdx.x;
    if (e >= E_EDGES) return;
    int s = src[e], d = dst[e];
    int pos = atomicAdd(&cursor[d], 1);
    csr_src[pos] = s;
    csr_nrm[pos] = dinv[s] * w[e] * dinv[d];
}
// one block per dst node; fuses self-loop + bias + ReLU; writes f32 + bf16
__global__ __launch_bounds__(256)
void gcn_gather_kernel(const int* __restrict__ start, const int* __restrict__ csr_src,
                       const float* __restrict__ csr_nrm, const float* __restrict__ xw,
                       const float* __restrict__ dinv, const float* __restrict__ b,
                       float* __restrict__ h, short* __restrict__ hb) {
    const int n = blockIdx.x, d = threadIdx.x;
    const int s0 = start[n], s1 = start[n + 1];
    float acc = 0.f;
    __shared__ int   ssrc[256];
    __shared__ float snrm[256];
    for (int base = s0; base < s1; base += 256) {
        const int cnt = min(256, s1 - base);
        __syncthreads();
        if (d < cnt) { ssrc[d] = csr_src[base + d]; snrm[d] = csr_nrm[base + d]; }
        __syncthreads();
        for (int j = 0; j < cnt; ++j)
            acc = fmaf(snrm[j], xw[(size_t)ssrc[j] * DM_ + d], acc);
    }
    const float di = dinv[n];
    float v = acc + di * di * xw[(size_t)n * DM_ + d] + b[d];
    v = fmaxf(v, 0.f);
    h[(size_t)n * DM_ + d] = v;
    hb[(size_t)n * DM_ + d] = f2b(v);
}

// ---------------------------------------------------------------------------
// LayerNorm(a+b); writes f32 (always) and bf16 (if outb != null)
// ---------------------------------------------------------------------------
__global__ __launch_bounds__(256)
void ln_kernel(const float* __restrict__ a, const float* __restrict__ b,
               const float* __restrict__ g, const float* __restrict__ be,
               float* __restrict__ outf, short* __restrict__ outb) {
    const int n = blockIdx.x, d = threadIdx.x;
    const size_t idx = (size_t)n * DM_ + d;
    float x = a[idx] + b[idx];
    float s = x;
    #pragma unroll
    for (int off = 32; off; off >>= 1) s += __shfl_xor(s, off);
    __shared__ float red[8];
    const int wid = d >> 6;
    if ((d & 63) == 0) red[wid] = s;
    __syncthreads();
    float mu = (red[0] + red[1] + red[2] + red[3]) * (1.f / 256.f);
    float c = x - mu;
    float q = c * c;
    #pragma unroll
    for (int off = 32; off; off >>= 1) q += __shfl_xor(q, off);
    if ((d & 63) == 0) red[4 + wid] = q;
    __syncthreads();
    float var = (red[4] + red[5] + red[6] + red[7]) * (1.f / 256.f);
    float v = c * rsqrtf(var + EPS_) * g[d] + be[d];
    outf[idx] = v;
    if (outb) outb[idx] = f2b(v);
}

// ---------------------------------------------------------------------------
extern "C" void kernel_launch(void* const* d_in, const int* in_sizes, int n_in,
                              void* d_out, int out_size, void* d_ws, size_t ws_size,
                              hipStream_t stream) {
    const float* x   = (const float*)d_in[0];
    const int*   ei  = (const int*)  d_in[1];
    const float* ew  = (const float*)d_in[2];
    const float* Wg  = (const float*)d_in[3];
    const float* bg  = (const float*)d_in[4];
    const float* inw = (const float*)d_in[5];
    const float* inb = (const float*)d_in[6];
    const float* ow  = (const float*)d_in[7];
    const float* ob  = (const float*)d_in[8];
    const float* l1w = (const float*)d_in[9];
    const float* l1b = (const float*)d_in[10];
    const float* l2w = (const float*)d_in[11];
    const float* l2b = (const float*)d_in[12];
    const float* g1  = (const float*)d_in[13];
    const float* b1  = (const float*)d_in[14];
    const float* g2  = (const float*)d_in[15];
    const float* b2  = (const float*)d_in[16];
    float* out = (float*)d_out;

    char* ws = (char*)d_ws;
    size_t off = 0;
    auto alloc = [&](size_t bytes) {
        void* p = ws + off;
        off += (bytes + 255) & ~(size_t)255;
        return p;
    };
    float* deg     = (float*)alloc((size_t)N_NODES * 4);
    int*   count   = (int*)  alloc((size_t)N_NODES * 4);
    int*   startA  = (int*)  alloc((size_t)(N_NODES + 1) * 4);
    int*   cursor  = (int*)  alloc((size_t)N_NODES * 4);
    int*   csr_src = (int*)  alloc((size_t)E_EDGES * 4);
    float* csr_nrm = (float*)alloc((size_t)E_EDGES * 4);
    short* xb    = (short*)alloc((size_t)N_NODES * DIN_ * 2);          // 4 MB
    short* WgT   = (short*)alloc((size_t)DM_ * DIN_ * 2);
    short* inwb  = (short*)alloc((size_t)768 * DM_ * 2);
    short* owb   = (short*)alloc((size_t)DM_ * DM_ * 2);
    short* l1wb  = (short*)alloc((size_t)DFF_ * DM_ * 2);
    short* l2wb  = (short*)alloc((size_t)DM_ * DFF_ * 2);
    float* xw    = (float*)alloc((size_t)N_NODES * DM_ * 4);           // 4 MB
    float* h     = (float*)alloc((size_t)N_NODES * DM_ * 4);
    short* hb    = (short*)alloc((size_t)N_NODES * DM_ * 2);
    short* qkvb  = (short*)alloc((size_t)N_NODES * 768 * 2);           // 6 MB
    short* VT    = (short*)alloc((size_t)DM_ * N_NODES * 2);           // 2 MB
    short* attnb = (short*)alloc((size_t)N_NODES * DM_ * 2);
    float* tmp   = (float*)alloc((size_t)N_NODES * DM_ * 4);
    float* h1    = (float*)alloc((size_t)N_NODES * DM_ * 4);
    short* h1b   = (short*)alloc((size_t)N_NODES * DM_ * 2);
    // shared region: {Opart bf16 + ml f32} during attention, ff1b during FFN
    size_t opart_b = (size_t)2 * NSPLIT * N_NODES * 128 * 2;           // 16.8 MB
    size_t ml_b    = (size_t)2 * NSPLIT * N_NODES * 2 * 4;             // 0.5 MB
    size_t ff1_b   = (size_t)N_NODES * DFF_ * 2;                       // 16 MB
    char*  R     = (char*)alloc(opart_b + ml_b > ff1_b ? opart_b + ml_b : ff1_b);
    short* Opart = (short*)R;
    float* ml    = (float*)(R + opart_b);
    short* ff1b  = (short*)R;
    (void)ws_size; (void)in_sizes; (void)n_in; (void)out_size;

    const int* srcI = ei;
    const int* dstI = ei + E_EDGES;

    // ---- casts ----
    castf2b_kernel<<<2048, 256, 0, stream>>>(x, xb, N_NODES * DIN_ / 4);
    wgt_kernel<<<dim3(16, 8), 256, 0, stream>>>(Wg, WgT);
    castf2b_kernel<<<192, 256, 0, stream>>>(inw, inwb, 768 * DM_ / 4);
    castf2b_kernel<<<64, 256, 0, stream>>>(ow, owb, DM_ * DM_ / 4);
    castf2b_kernel<<<512, 256, 0, stream>>>(l1w, l1wb, DFF_ * DM_ / 4);
    castf2b_kernel<<<512, 256, 0, stream>>>(l2w, l2wb, DM_ * DFF_ / 4);

    // ---- GCN ----
    deg_init_kernel<<<16, 256, 0, stream>>>(deg, count);
    deg_accum_kernel<<<E_EDGES / 256, 256, 0, stream>>>(dstI, ew, deg, count);
    dinv_kernel<<<16, 256, 0, stream>>>(deg);
    csr_scan_kernel<<<1, 256, 0, stream>>>(count, startA, cursor);
    csr_fill_kernel<<<E_EDGES / 256, 256, 0, stream>>>(srcI, dstI, ew, deg, cursor,
                                                       csr_src, csr_nrm);
    mgemm_kernel<false, false, false><<<dim3(2, 32), 256, 0, stream>>>(
        xb, WgT, nullptr, xw, nullptr, N_NODES, DM_, DIN_, DIN_, DIN_, DM_, 0);
    gcn_gather_kernel<<<N_NODES, 256, 0, stream>>>(startA, csr_src, csr_nrm, xw,
                                                   deg, bg, h, hb);

    // ---- QKV ----
    mgemm_kernel<true, false, false><<<dim3(6, 32), 256, 0, stream>>>(
        hb, inwb, inb, nullptr, qkvb, N_NODES, 768, DM_, DM_, DM_, 768, 0);
    vt_kernel<<<dim3(128, 8), 256, 0, stream>>>(qkvb, VT);

    // ---- flash attention (KV-split, XCD-local) + combine ----
    fattn_kernel<<<1024, 256, 0, stream>>>(qkvb, VT, Opart, ml);
    attn_combine_kernel<<<dim3(N_NODES, 2), 128, 0, stream>>>(Opart, ml, attnb);

    // ---- out_proj + LN1 ----
    mgemm_kernel<false, false, false><<<dim3(2, 32), 256, 0, stream>>>(
        attnb, owb, ob, tmp, nullptr, N_NODES, DM_, DM_, DM_, DM_, DM_, 0);
    ln_kernel<<<N_NODES, 256, 0, stream>>>(h, tmp, g1, b1, h1, h1b);

    // ---- FFN ----
    mgemm_kernel<true, true, false><<<dim3(16, 32), 256, 0, stream>>>(
        h1b, l1wb, l1b, nullptr, ff1b, N_NODES, DFF_, DM_, DM_, DM_, DFF_, 0);
    hipMemsetAsync(tmp, 0, (size_t)N_NODES * DM_ * 4, stream);
    mgemm_kernel<false, false, true><<<dim3(2, 32, 4), 256, 0, stream>>>(
        ff1b, l2wb, l2b, tmp, nullptr, N_NODES, DM_, DFF_, DFF_, DFF_, DM_, 512);
    ln_kernel<<<N_NODES, 256, 0, stream>>>(h1, tmp, g2, b2, out, nullptr);
}